// Round 14
// baseline (611.709 us; speedup 1.0000x reference)
//
#include <hip/hip_runtime.h>

// Heat equation, 2 materials, N=512, 499 steps, all frames written.
// R14: K=48 steps/launch, 11 dispatches (10x48 + 19), 512-thread blocks.
// Region = 128x128 halo'd (owned 32x32, halo 48). Thread = 8-row x 4-col
// strip; strip = 32 lanes exactly (c = t&31, u = t>>5) so DPP lane shifts
// cross strips ONLY at c==0 -> region-edge column -> trapezoid-junk-safe.
// Interior 6 rows are register-only; per step each thread does 2 ghost
// ds_read_b128 + 2 boundary ds_write_b128. R9's nearest-neighbor wave-flag
// protocol (no block barrier in loop). Frame stores fully async.

#define GN 512
#define NSTEPS 499
#define MBND 256
#define INV_DX2 261121.0f     // 511^2 = 1/dx^2
#define DT 5e-7f

#define TO 32                 // owned tile edge
#define KH 48                 // steps per full launch = halo width
#define LOAD 128              // TO + 2*KH
#define H 8                   // rows per strip
#define NSTRIP 16             // LOAD / H
#define PTS (GN * GN)

// wave-wide lane shifts; out-of-range lanes keep own value (bound_ctrl=0,
// old=src). Crossings at lane 0/32 are c==0 -> left edge of the region;
// lane 31/63 feed c==31 -> right edge. Both outside the validity trapezoid.
__device__ __forceinline__ float dpp_shr1(float x) {  // lane i <- i-1
    int v = __builtin_amdgcn_update_dpp(__float_as_int(x), __float_as_int(x),
                                        0x138, 0xf, 0xf, false);
    return __int_as_float(v);
}
__device__ __forceinline__ float dpp_shl1(float x) {  // lane i <- i+1
    int v = __builtin_amdgcn_update_dpp(__float_as_int(x), __float_as_int(x),
                                        0x130, 0xf, 0xf, false);
    return __int_as_float(v);
}

struct Prm {
    float Ac[4]; bool ifc[4]; bool bcl[4];
    float k1, k2, invk;
    bool aI, aC, aR;
};

__device__ __forceinline__ void srow(const float x[4], const float up[4],
                                     const float dn[4], float out[4],
                                     const Prm& p, bool brF)
{
    const float lf = dpp_shr1(x[3]);
    const float rg = dpp_shl1(x[0]);
    const float le[4] = {lf, x[0], x[1], x[2]};
    const float ri[4] = {x[1], x[2], x[3], rg};
    #pragma unroll
    for (int j = 0; j < 4; ++j) {
        float v = fmaf(p.Ac[j], fmaf(-4.0f, x[j], (up[j] + dn[j]) + (le[j] + ri[j])), x[j]);
        if (p.aI) v = p.ifc[j] ? (p.k1 * ri[j] + p.k2 * le[j]) * p.invk : v; // OLD nbrs
        if (p.aC) v = p.bcl[j] ? 0.0f : v;
        if (p.aR) v = brF ? 0.0f : v;
        out[j] = v;
    }
}

__device__ __forceinline__ void ld4(float d[4], const float* s) {
    const float4 v = *(const float4*)s;
    d[0] = v.x; d[1] = v.y; d[2] = v.z; d[3] = v.w;
}

template<int STEPS>   // 48 (full) or 19 (tail)
__global__ __launch_bounds__(512) void heat_multi(
    const float* __restrict__ Tin, float* __restrict__ outBase,
    const float* __restrict__ k1p, const float* __restrict__ k2p,
    const float* __restrict__ a1p, const float* __restrict__ a2p)
{
    // S[parity][strip][0 = strip row 0 (top), 1 = strip row 7 (bottom)][col]
    __shared__ float S[2][NSTRIP][2][LOAD];
    __shared__ int fl[8];

    const int t = threadIdx.x;               // 0..511
    const int c = t & 31;                    // col group (4 cols)
    const int u = t >> 5;                    // strip 0..15 (8 rows)
    const int w = t >> 6;                    // wave 0..7
    const int bi = blockIdx.x >> 4;          // 16x16 tile grid
    const int bj = blockIdx.x & 15;
    const int gi0 = bi * TO - KH;
    const int gj0 = bj * TO - KH;
    const int gr0 = gi0 + H * u;             // first of my 8 rows
    const int gc0 = gj0 + 4 * c;             // first of my 4 cols

    Prm p;
    p.k1 = k1p[0]; p.k2 = k2p[0];
    const float a1 = a1p[0], a2 = a2p[0];
    p.invk = 1.0f / (p.k1 + p.k2);
    #pragma unroll
    for (int j = 0; j < 4; ++j) {
        const int gjj = gc0 + j;
        p.Ac[j]  = (DT * INV_DX2) * ((gjj < MBND) ? a1 : a2);
        p.ifc[j] = (gjj == MBND - 1);
        p.bcl[j] = (gjj <= 0) || (gjj >= GN - 1);
    }
    p.aI = (gj0 <= MBND - 1) && (MBND - 1 <= gj0 + LOAD - 1);
    p.aC = (gj0 <= 0) || (gj0 + LOAD - 1 >= GN - 1);
    p.aR = (gi0 <= 0) || (gi0 + LOAD - 1 >= GN - 1);

    bool brr[H];
    #pragma unroll
    for (int r = 0; r < H; ++r) {
        const int gr = gr0 + r;
        brr[r] = (gr <= 0) || (gr >= GN - 1);
    }

    // ---- stage 8 own rows + 2 ghost rows straight from global (coalesced)
    const bool okC = ((unsigned)gc0 < (unsigned)GN);
    float R[H][4], U[4], Dn[4];
    #pragma unroll
    for (int r = 0; r < H; ++r) {
        const int gr = gr0 + r;
        if (okC && (unsigned)gr < (unsigned)GN) ld4(R[r], &Tin[(long)gr * GN + gc0]);
        else { R[r][0] = R[r][1] = R[r][2] = R[r][3] = 0.0f; }
    }
    { const int gr = gr0 - 1;
      if (okC && (unsigned)gr < (unsigned)GN) ld4(U, &Tin[(long)gr * GN + gc0]);
      else { U[0] = U[1] = U[2] = U[3] = 0.0f; } }
    { const int gr = gr0 + H;
      if (okC && (unsigned)gr < (unsigned)GN) ld4(Dn, &Tin[(long)gr * GN + gc0]);
      else { Dn[0] = Dn[1] = Dn[2] = Dn[3] = 0.0f; } }

    if (t < 8) fl[t] = 0;                    // "state 0 published"
    __syncthreads();                         // the ONLY block-wide barrier

    const int um  = (u > 0) ? u - 1 : 0;     // clamped -> junk, trapezoid-safe
    const int up_ = (u < NSTRIP - 1) ? u + 1 : NSTRIP - 1;
    const int wm  = (w > 0) ? w - 1 : 0;
    const int wp  = (w < 7) ? w + 1 : 7;

    // owned tile = whole strips 6..9 x col groups 12..19 (local [48,80)^2)
    const bool own = (u >= 6) && (u <= 9) && (c >= 12) && (c <= 19);
    float* dst = outBase + ((long)gr0 * GN + gc0);

    #pragma unroll 2
    for (int s = 1; s <= STEPS; ++s) {
        // 1) wait for neighbor waves' state s-1, then read ghost rows.
        //    strips u+-1 live in waves w-1..w+1; same-wave order is implicit.
        if (s > 1) {
            while (__atomic_load_n(&fl[wm], __ATOMIC_ACQUIRE) < s - 1 ||
                   __atomic_load_n(&fl[wp], __ATOMIC_ACQUIRE) < s - 1)
                __builtin_amdgcn_s_sleep(1);
            const int rp = (s - 1) & 1;
            ld4(U,  &S[rp][um][1][4 * c]);   // row 8u-1 @ s-1
            ld4(Dn, &S[rp][up_][0][4 * c]);  // row 8u+8 @ s-1
        }

        // 2) strip boundary rows first — they feed the exchange
        float n0[4], n7[4];
        srow(R[0], U,    R[1], n0, p, brr[0]);
        srow(R[7], R[6], Dn,   n7, p, brr[7]);

        // 3) publish + release flag (release orders the ds_writes)
        if (s < STEPS) {
            const int wb = s & 1;
            *(float4*)&S[wb][u][0][4 * c] = make_float4(n0[0], n0[1], n0[2], n0[3]);
            *(float4*)&S[wb][u][1][4 * c] = make_float4(n7[0], n7[1], n7[2], n7[3]);
            if ((t & 63) == 0)
                __atomic_store_n(&fl[w], s, __ATOMIC_RELEASE);
        }

        // 4) interior rows 1..6: rolling sweep, old values carried in prev
        float prev[4];
        #pragma unroll
        for (int j = 0; j < 4; ++j) { prev[j] = R[0][j]; R[0][j] = n0[j]; }
        #pragma unroll
        for (int i = 1; i <= 6; ++i) {
            float nx[4];
            srow(R[i], prev, R[i + 1], nx, p, brr[i]);   // R[i+1] still old
            #pragma unroll
            for (int j = 0; j < 4; ++j) { prev[j] = R[i][j]; R[i][j] = nx[j]; }
        }
        #pragma unroll
        for (int j = 0; j < 4; ++j) R[7][j] = n7[j];

        // 5) stream owned strip rows (async; nothing drains vmcnt in-loop)
        if (own) {
            #pragma unroll
            for (int i = 0; i < H; ++i)
                *(float4*)(dst + (long)i * GN) =
                    make_float4(R[i][0], R[i][1], R[i][2], R[i][3]);
        }
        dst += (long)PTS;
    }
}

extern "C" void kernel_launch(void* const* d_in, const int* in_sizes, int n_in,
                              void* d_out, int out_size, void* d_ws, size_t ws_size,
                              hipStream_t stream)
{
    const float* u0 = (const float*)d_in[0];
    const float* k1 = (const float*)d_in[1];
    const float* k2 = (const float*)d_in[2];
    const float* a1 = (const float*)d_in[3];
    const float* a2 = (const float*)d_in[4];
    float* out = (float*)d_out;

    const float* src = u0;
    int done = 0;
    while (done < NSTEPS) {
        int steps = NSTEPS - done;
        if (steps > KH) steps = KH;
        float* ob = out + (size_t)done * PTS;
        if (steps == KH)
            heat_multi<KH><<<256, 512, 0, stream>>>(src, ob, k1, k2, a1, a2);
        else  // NSTEPS = 10*48 + 19 -> remainder is always 19
            heat_multi<19><<<256, 512, 0, stream>>>(src, ob, k1, k2, a1, a2);
        src = ob + (size_t)(steps - 1) * PTS;
        done += steps;
    }
}

// Round 15
// 389.652 us; speedup vs baseline: 1.5699x; 1.5699x over previous
//
#include <hip/hip_runtime.h>

// Heat equation, 2 materials, N=512, 499 steps, all frames written.
// R15: K=16 steps/launch, 32 dispatches, 256-thread blocks.
// Thread = 4-row x 4-col strip of a 64x64 halo'd region (owned 32x32).
// c = t&15 -> 16 col-groups == one 16-lane DPP row (R13's misalignment
// fixed): DPP left/right junk only at region-edge columns (trapezoid-safe).
// Middle 2 rows of each strip are register-private; cross-strip traffic =
// 2 ghost ds_read_b128 + 2 boundary ds_write_b128 per thread per step.
// R9's nearest-neighbor wave-flag protocol (4 waves, no block barrier).
// Ghost reads issue first; middle rows compute under their latency.
// Frame stores fully async (nothing drains vmcnt in the loop).

#define GN 512
#define NSTEPS 499
#define MBND 256
#define INV_DX2 261121.0f     // 511^2 = 1/dx^2
#define DT 5e-7f

#define TO 32                 // owned tile edge
#define KMAX 16               // steps per launch (= trapezoid margin)
#define LOAD 64               // TO + 2*KMAX
#define LSTR 68               // padded LDS row stride (floats)
#define PTS (GN * GN)

// DPP shifts within 16-lane rows. Out-of-range lanes keep their own value
// (bound_ctrl=0, old=src) -> junk only at region-edge columns.
__device__ __forceinline__ float dpp_row_shr1(float x) {  // lane i <- i-1
    int v = __builtin_amdgcn_update_dpp(__float_as_int(x), __float_as_int(x),
                                        0x111, 0xf, 0xf, false);
    return __int_as_float(v);
}
__device__ __forceinline__ float dpp_row_shl1(float x) {  // lane i <- i+1
    int v = __builtin_amdgcn_update_dpp(__float_as_int(x), __float_as_int(x),
                                        0x101, 0xf, 0xf, false);
    return __int_as_float(v);
}

struct Prm {
    float Ac[4]; bool ifc[4]; bool bcl[4];
    float k1, k2, invk;
    bool aI, aC, aR;
};

__device__ __forceinline__ void srow(const float x[4], const float up[4],
                                     const float dn[4], float out[4],
                                     const Prm& p, bool brF)
{
    const float lf = dpp_row_shr1(x[3]);
    const float rg = dpp_row_shl1(x[0]);
    const float le[4] = {lf, x[0], x[1], x[2]};
    const float ri[4] = {x[1], x[2], x[3], rg};
    #pragma unroll
    for (int j = 0; j < 4; ++j) {
        float v = fmaf(p.Ac[j], fmaf(-4.0f, x[j], (up[j] + dn[j]) + (le[j] + ri[j])), x[j]);
        if (p.aI) v = p.ifc[j] ? (p.k1 * ri[j] + p.k2 * le[j]) * p.invk : v; // OLD nbrs
        if (p.aC) v = p.bcl[j] ? 0.0f : v;
        if (p.aR) v = brF ? 0.0f : v;
        out[j] = v;
    }
}

__device__ __forceinline__ void ld4(float d[4], const float* s) {
    const float4 v = *(const float4*)s;
    d[0] = v.x; d[1] = v.y; d[2] = v.z; d[3] = v.w;
}

template<int STEPS>   // 16 (full) or 3 (tail)
__global__ __launch_bounds__(256) void heat_multi(
    const float* __restrict__ Tin, float* __restrict__ outBase,
    const float* __restrict__ k1p, const float* __restrict__ k2p,
    const float* __restrict__ a1p, const float* __restrict__ a2p)
{
    // full 64-row layout (rows 4u+1, 4u+2 never written -> wasted space,
    // but identical conflict-free addressing to R9)
    __shared__ float Sb[2][LOAD][LSTR];
    __shared__ int fl[4];

    const int t = threadIdx.x;               // 0..255
    const int c = t & 15;                    // col group == DPP row lane
    const int u = t >> 4;                    // strip 0..15 (4 rows each)
    const int w = t >> 6;                    // wave 0..3
    const int bi = blockIdx.x >> 4;          // 16x16 tile grid
    const int bj = blockIdx.x & 15;
    const int gi0 = bi * TO - KMAX;
    const int gj0 = bj * TO - KMAX;
    const int lj0 = 4 * c;
    const int gr0 = gi0 + 4 * u;             // first of my 4 rows
    const int gc0 = gj0 + lj0;               // first of my 4 cols

    Prm p;
    p.k1 = k1p[0]; p.k2 = k2p[0];
    const float a1 = a1p[0], a2 = a2p[0];
    p.invk = 1.0f / (p.k1 + p.k2);
    #pragma unroll
    for (int j = 0; j < 4; ++j) {
        const int gjj = gc0 + j;
        p.Ac[j]  = (DT * INV_DX2) * ((gjj < MBND) ? a1 : a2);
        p.ifc[j] = (gjj == MBND - 1);
        p.bcl[j] = (gjj <= 0) || (gjj >= GN - 1);
    }
    p.aI = (bj == 7) || (bj == 8);
    p.aC = (bj == 0) || (bj == 15);
    p.aR = (bi == 0) || (bi == 15);

    bool brr[4];
    #pragma unroll
    for (int r = 0; r < 4; ++r) {
        const int gr = gr0 + r;
        brr[r] = (gr <= 0) || (gr >= GN - 1);
    }

    // ---- stage 4 own rows + 2 ghost rows straight from global (coalesced)
    const bool okC = ((unsigned)gc0 < (unsigned)GN);
    float R[4][4], U[4], Dn[4];
    #pragma unroll
    for (int r = 0; r < 4; ++r) {
        const int gr = gr0 + r;
        if (okC && (unsigned)gr < (unsigned)GN) ld4(R[r], &Tin[(long)gr * GN + gc0]);
        else { R[r][0] = R[r][1] = R[r][2] = R[r][3] = 0.0f; }
    }
    { const int gr = gr0 - 1;
      if (okC && (unsigned)gr < (unsigned)GN) ld4(U, &Tin[(long)gr * GN + gc0]);
      else { U[0] = U[1] = U[2] = U[3] = 0.0f; } }
    { const int gr = gr0 + 4;
      if (okC && (unsigned)gr < (unsigned)GN) ld4(Dn, &Tin[(long)gr * GN + gc0]);
      else { Dn[0] = Dn[1] = Dn[2] = Dn[3] = 0.0f; } }

    if (t < 4) fl[t] = 0;                    // "state 0 published"
    __syncthreads();                         // the ONLY block-wide barrier

    // ghost source rows (always written rows: 4v or 4v+3), clamped = junk-safe
    const int ru = (u > 0)  ? 4 * u - 1 : 0;
    const int rd = (u < 15) ? 4 * u + 4 : LOAD - 1;
    const int r0 = 4 * u, r3 = 4 * u + 3;    // my published rows
    const int wm = (w > 0) ? w - 1 : 0;
    const int wp = (w < 3) ? w + 1 : 3;

    // owned tile: strips 4..11 x col groups 4..11 (local [16,48)^2)
    const bool own = (u >= 4) && (u < 12) && (c >= 4) && (c < 12);
    float* dst = outBase + ((long)gr0 * GN + gc0);

    #pragma unroll
    for (int s = 1; s <= STEPS; ++s) {
        // 1) wait for neighbor waves' state s-1, then issue ghost reads
        if (s > 1) {
            while (__atomic_load_n(&fl[wm], __ATOMIC_ACQUIRE) < s - 1 ||
                   __atomic_load_n(&fl[wp], __ATOMIC_ACQUIRE) < s - 1)
                __builtin_amdgcn_s_sleep(1);
            const int rp = (s - 1) & 1;
            ld4(U,  &Sb[rp][ru][lj0]);       // row 4u-1 @ s-1
            ld4(Dn, &Sb[rp][rd][lj0]);       // row 4u+4 @ s-1
        }

        // 2) middle rows first (register-only; hides ghost-read latency)
        float n1[4], n2[4];
        srow(R[1], R[0], R[2], n1, p, brr[1]);
        srow(R[2], R[1], R[3], n2, p, brr[2]);

        // 3) boundary rows (consume U/Dn)
        float n0[4], n3[4];
        srow(R[0], U,    R[1], n0, p, brr[0]);
        srow(R[3], R[2], Dn,   n3, p, brr[3]);

        // 4) publish + release flag (release orders the ds_writes)
        if (s < STEPS) {
            const int wb = s & 1;
            *(float4*)&Sb[wb][r0][lj0] = make_float4(n0[0], n0[1], n0[2], n0[3]);
            *(float4*)&Sb[wb][r3][lj0] = make_float4(n3[0], n3[1], n3[2], n3[3]);
            if ((t & 63) == 0)
                __atomic_store_n(&fl[w], s, __ATOMIC_RELEASE);
        }

        // 5) stream owned strip (async; nothing drains vmcnt in the loop)
        if (own) {
            *(float4*)(dst)          = make_float4(n0[0], n0[1], n0[2], n0[3]);
            *(float4*)(dst + GN)     = make_float4(n1[0], n1[1], n1[2], n1[3]);
            *(float4*)(dst + 2 * GN) = make_float4(n2[0], n2[1], n2[2], n2[3]);
            *(float4*)(dst + 3 * GN) = make_float4(n3[0], n3[1], n3[2], n3[3]);
        }
        dst += (long)PTS;

        #pragma unroll
        for (int j = 0; j < 4; ++j) {
            R[0][j] = n0[j]; R[1][j] = n1[j]; R[2][j] = n2[j]; R[3][j] = n3[j];
        }
    }
}

extern "C" void kernel_launch(void* const* d_in, const int* in_sizes, int n_in,
                              void* d_out, int out_size, void* d_ws, size_t ws_size,
                              hipStream_t stream)
{
    const float* u0 = (const float*)d_in[0];
    const float* k1 = (const float*)d_in[1];
    const float* k2 = (const float*)d_in[2];
    const float* a1 = (const float*)d_in[3];
    const float* a2 = (const float*)d_in[4];
    float* out = (float*)d_out;

    const float* src = u0;
    int done = 0;
    while (done < NSTEPS) {
        int steps = NSTEPS - done;
        if (steps > KMAX) steps = KMAX;
        float* ob = out + (size_t)done * PTS;
        if (steps == KMAX)
            heat_multi<KMAX><<<256, 256, 0, stream>>>(src, ob, k1, k2, a1, a2);
        else  // NSTEPS = 31*16 + 3 -> remainder is always 3
            heat_multi<3><<<256, 256, 0, stream>>>(src, ob, k1, k2, a1, a2);
        src = ob + (size_t)(steps - 1) * PTS;
        done += steps;
    }
}

// Round 16
// 348.156 us; speedup vs baseline: 1.7570x; 1.1192x over previous
//
#include <hip/hip_runtime.h>

// Heat equation, 2 materials, N=512, 499 steps, all frames written.
// Temporal tiling: K=16 steps/launch, 32 dispatches, 1024-thread blocks,
// thread = 1x4 strip (row ty, cols lj0..lj0+3) of a 64x64 halo'd region.
// R16 = R9 engine with ONE change: the two per-step neighbor-flag loads
// are merged into a single ds_read_b64 mailbox poll (s_sleep kept in the
// spin; explicit lgkmcnt(0) release before the flag store). Everything
// else identical to R9: nearest-neighbor wave sync, DPP left/right,
// 2-parity LDS buffers, fully async frame stores.

#define GN 512
#define NSTEPS 499
#define MBND 256
#define INV_DX2 261121.0f     // 511^2 = 1/dx^2
#define DT 5e-7f

#define TO 32                 // owned tile edge
#define KMAX 16               // steps per launch (= trapezoid margin)
#define LOAD 64               // TO + 2*KMAX
#define LSTR 68               // padded LDS row stride (floats)

// DPP shifts within 16-lane rows (= one ty row of threads). Out-of-range
// lanes keep their own value (bound_ctrl=0, old=src) -> junk only at
// region edges, outside the validity trapezoid.
__device__ __forceinline__ float dpp_row_shr1(float x) {  // lane i <- i-1
    int v = __builtin_amdgcn_update_dpp(__float_as_int(x), __float_as_int(x),
                                        0x111, 0xf, 0xf, false);
    return __int_as_float(v);
}
__device__ __forceinline__ float dpp_row_shl1(float x) {  // lane i <- i+1
    int v = __builtin_amdgcn_update_dpp(__float_as_int(x), __float_as_int(x),
                                        0x101, 0xf, 0xf, false);
    return __int_as_float(v);
}

struct Prm {
    float Ac[4]; bool ifc[4]; bool bcl[4];
    float k1, k2, invk;
    bool aI, aC, aR;
};

// One stencil row update: x = row values, up/dn = vertical neighbors.
__device__ __forceinline__ void srow(const float x[4], const float up[4],
                                     const float dn[4], float out[4],
                                     const Prm& p, bool brF)
{
    const float lf = dpp_row_shr1(x[3]);
    const float rg = dpp_row_shl1(x[0]);
    const float le[4] = {lf, x[0], x[1], x[2]};
    const float ri[4] = {x[1], x[2], x[3], rg};
    #pragma unroll
    for (int j = 0; j < 4; ++j) {
        float v = fmaf(p.Ac[j], fmaf(-4.0f, x[j], (up[j] + dn[j]) + (le[j] + ri[j])), x[j]);
        if (p.aI) v = p.ifc[j] ? (p.k1 * ri[j] + p.k2 * le[j]) * p.invk : v; // OLD nbrs
        if (p.aC) v = p.bcl[j] ? 0.0f : v;
        if (p.aR) v = brF ? 0.0f : v;
        out[j] = v;
    }
}

__device__ __forceinline__ void ld4(float d[4], const float* s) {
    const float4 v = *(const float4*)s;
    d[0] = v.x; d[1] = v.y; d[2] = v.z; d[3] = v.w;
}

template<int STEPS>   // 16 (full) or 3 (tail)
__global__ __launch_bounds__(1024) void heat_multi(
    const float* __restrict__ Tin, float* __restrict__ outBase,
    const float* __restrict__ k1p, const float* __restrict__ k2p,
    const float* __restrict__ a1p, const float* __restrict__ a2p)
{
    __shared__ float Sb[2][LOAD][LSTR];
    // mbx[w+1] = wave w's mailbox: .x = progress of wave w-1 (written by
    // w-1 lane0), .y = progress of wave w+1 (written by w+1 lane1).
    // mbx[0], mbx[17] are write-only guards. Sentinels: mbx[1].x and
    // mbx[16].y = INT_MAX (edge waves have no neighbor on that side).
    __shared__ int2 mbx[18];

    const int t  = threadIdx.x;              // 0..1023
    const int bi = blockIdx.x >> 4;          // 16x16 tile grid
    const int bj = blockIdx.x & 15;
    const int gi0 = bi * TO - KMAX;
    const int gj0 = bj * TO - KMAX;

    const int tx = t & 15, ty = t >> 4;      // 64 rows x 16 col-groups
    const int w  = t >> 6;                   // wave id 0..15
    const int lane = t & 63;
    const int lj0 = tx * 4;

    // ---- stage region @t0 into Sb[0]; own float4 == (ty,lj0) assignment
    float C[4];
    {
        const bool innerB = (gi0 >= 0) && (gi0 + LOAD <= GN) &&
                            (gj0 >= 0) && (gj0 + LOAD <= GN);
        float4 v;
        if (innerB) {
            v = *(const float4*)&Tin[(size_t)(gi0 + ty) * GN + (gj0 + lj0)];
        } else {
            const int gi_ = gi0 + ty;
            float tmp[4];
            #pragma unroll
            for (int e = 0; e < 4; ++e) {
                const int gj_ = gj0 + lj0 + e;
                tmp[e] = ((unsigned)gi_ < GN && (unsigned)gj_ < GN)
                         ? Tin[(size_t)gi_ * GN + gj_] : 0.0f;
            }
            v = make_float4(tmp[0], tmp[1], tmp[2], tmp[3]);
        }
        *(float4*)&Sb[0][ty][lj0] = v;
        C[0] = v.x; C[1] = v.y; C[2] = v.z; C[3] = v.w;
    }
    if (t < 18) {
        mbx[t].x = (t == 1)  ? 0x7fffffff : 0;   // "state 0 published"
        mbx[t].y = (t == 16) ? 0x7fffffff : 0;
    }
    __syncthreads();                         // the ONLY block-wide barrier

    // clamped neighbor-row indices (junk-safe: outside trapezoid)
    const int rm1 = (ty >= 1) ? ty - 1 : 0;
    const int rp1 = (ty <= LOAD - 2) ? ty + 1 : LOAD - 1;

    Prm p;
    p.k1 = k1p[0]; p.k2 = k2p[0];
    const float a1 = a1p[0], a2 = a2p[0];
    p.invk = 1.0f / (p.k1 + p.k2);
    #pragma unroll
    for (int j = 0; j < 4; ++j) {
        const int gj_ = gj0 + lj0 + j;
        p.Ac[j]  = (DT * INV_DX2) * ((gj_ < MBND) ? a1 : a2);
        p.ifc[j] = (gj_ == MBND - 1);
        p.bcl[j] = (gj_ <= 0) || (gj_ >= GN - 1);
    }
    p.aI = (bj == 7) || (bj == 8);
    p.aC = (bj == 0) || (bj == 15);
    p.aR = (bi == 0) || (bi == 15);

    const int gi = gi0 + ty;
    const bool br0 = (gi <= 0) || (gi >= GN - 1);

    const bool own = (tx >= 4) && (tx < 12) && (ty >= KMAX) && (ty < KMAX + TO);
    float* dst = outBase + ((long)gi * GN + (gj0 + lj0));

    // flag-write address for the 2 active lanes (lane0 -> wave w+1's .x,
    // lane1 -> wave w-1's .y); guards absorb edge writes.
    volatile int* fla = (lane == 0) ? (volatile int*)&mbx[w + 2].x
                                    : (volatile int*)&mbx[w].y;

    #pragma unroll
    for (int s = 1; s <= STEPS; ++s) {
        // 1) wait until both neighbor waves published state s-1
        //    (ONE ds_read_b64 poll; s_sleep between failed polls)
        if (s > 1) {
            const volatile long long* pm = (const volatile long long*)&mbx[w + 1];
            while (true) {
                const long long v = *pm;
                if ((int)v >= s - 1 && (int)(v >> 32) >= s - 1) break;
                __builtin_amdgcn_s_sleep(1);
            }
            asm volatile("" ::: "memory");   // no Sb reads hoisted above
        }
        // 2) read vertical neighbors (state s-1)
        const float (*Rb)[LSTR] = Sb[(s - 1) & 1];
        float B[4], D[4];
        ld4(B, &Rb[rm1][lj0]);
        ld4(D, &Rb[rp1][lj0]);

        // 3) compute state s for own row
        float nC[4];
        srow(C, B, D, nC, p, br0);

        // 4) publish row, drain LDS pipe, then raise flags (2 lanes)
        if (s < STEPS) {
            float (*Wb)[LSTR] = Sb[s & 1];
            *(float4*)&Wb[ty][lj0] = make_float4(nC[0], nC[1], nC[2], nC[3]);
            asm volatile("s_waitcnt lgkmcnt(0)" ::: "memory");  // publish visible
            if (lane < 2) *fla = s;
            asm volatile("" ::: "memory");
        }
        C[0] = nC[0]; C[1] = nC[1]; C[2] = nC[2]; C[3] = nC[3];

        // 5) stream owned strip (async; nothing in the loop drains vmcnt)
        if (own) *(float4*)dst = make_float4(C[0], C[1], C[2], C[3]);
        dst += (long)GN * GN;
    }
}

extern "C" void kernel_launch(void* const* d_in, const int* in_sizes, int n_in,
                              void* d_out, int out_size, void* d_ws, size_t ws_size,
                              hipStream_t stream)
{
    const float* u0 = (const float*)d_in[0];
    const float* k1 = (const float*)d_in[1];
    const float* k2 = (const float*)d_in[2];
    const float* a1 = (const float*)d_in[3];
    const float* a2 = (const float*)d_in[4];
    float* out = (float*)d_out;

    const int pts = GN * GN;
    const float* src = u0;
    int done = 0;
    while (done < NSTEPS) {
        int steps = NSTEPS - done;
        if (steps > KMAX) steps = KMAX;
        float* ob = out + (size_t)done * pts;
        if (steps == KMAX)
            heat_multi<KMAX><<<256, 1024, 0, stream>>>(src, ob, k1, k2, a1, a2);
        else  // NSTEPS = 31*16 + 3 -> remainder is always 3
            heat_multi<3><<<256, 1024, 0, stream>>>(src, ob, k1, k2, a1, a2);
        src = ob + (size_t)(steps - 1) * pts;
        done += steps;
    }
}